// Round 1
// baseline (903.836 us; speedup 1.0000x reference)
//
#include <hip/hip_runtime.h>
#include <math.h>

#define NTOK 1024
#define DDIM 512

__device__ __forceinline__ float4 ld4(const float* p){ return *(const float4*)p; }
__device__ __forceinline__ void st4(float* p, float4 v){ *(float4*)p = v; }

// ---------------- LayerNorm over D=512 with affine ----------------
__global__ __launch_bounds__(256) void ln_rows(const float* __restrict__ x,
    const float* __restrict__ w, const float* __restrict__ b, float* __restrict__ y) {
  int row = blockIdx.x, t = threadIdx.x;
  const float* xr = x + ((size_t)row << 9);
  float v0 = xr[t], v1 = xr[t + 256];
  float s = v0 + v1, q = v0*v0 + v1*v1;
  #pragma unroll
  for (int off = 1; off < 64; off <<= 1) { s += __shfl_xor(s, off); q += __shfl_xor(q, off); }
  __shared__ float ls[4], lq[4], mb[2];
  int wv = t >> 6;
  if ((t & 63) == 0) { ls[wv] = s; lq[wv] = q; }
  __syncthreads();
  if (t == 0) {
    float S = ls[0]+ls[1]+ls[2]+ls[3];
    float Q = lq[0]+lq[1]+lq[2]+lq[3];
    float m = S * (1.f/512.f);
    float var = Q * (1.f/512.f) - m*m;
    mb[0] = m; mb[1] = 1.f / sqrtf(var + 1e-5f);
  }
  __syncthreads();
  float m = mb[0], inv = mb[1];
  float* yr = y + ((size_t)row << 9);
  yr[t]       = (v0 - m) * inv * w[t] + b[t];
  yr[t + 256] = (v1 - m) * inv * w[t + 256] + b[t + 256];
}

// ---------------- per-head LN over DH=32 (no affine), in place; Q and K ----------------
__global__ __launch_bounds__(256) void qk_ln(float* __restrict__ Q, float* __restrict__ K) {
  float* P = blockIdx.y ? K : Q;
  int t = threadIdx.x;
  int row = blockIdx.x * 8 + (t >> 5);
  int l = t & 31;
  float* p = P + ((size_t)row << 5);
  float x = p[l];
  float s = x, q = x*x;
  #pragma unroll
  for (int off = 16; off; off >>= 1) { s += __shfl_xor(s, off, 32); q += __shfl_xor(q, off, 32); }
  float m = s * (1.f/32.f);
  float var = q * (1.f/32.f) - m*m;
  float inv = 1.f / sqrtf(var + 1e-5f);
  p[l] = (x - m) * inv;
}

// ---------------- generic fp32 GEMM, M=1024 rows, tile 64x64x16, 4x4/thread ----------------
// MODE 0: C = A@B            (plain, row-major Nd)
// MODE 1: head-scatter: C[(c>>5)*1024 + r][c&31] (layout (H,N,32))
// MODE 2: C = A@B + X        (residual)
// MODE 3: C = silu(A@B) * X
template<int MODE>
__global__ __launch_bounds__(256) void gemm64(const float* __restrict__ A,
    const float* __restrict__ B, float* __restrict__ C, const float* __restrict__ X,
    int Kd, int Nd) {
  __shared__ float As[16][68];
  __shared__ float Bs[16][64];
  int t = threadIdx.x;
  int bm = blockIdx.y << 6, bn = blockIdx.x << 6;
  int tr = t >> 4, tc = t & 15;
  int ar = t >> 2, ac = (t & 3) << 2;
  int bk = t >> 4, bc = (t & 15) << 2;
  float acc[4][4] = {};
  for (int k0 = 0; k0 < Kd; k0 += 16) {
    float4 a4 = ld4(A + (size_t)(bm + ar) * Kd + k0 + ac);
    float4 b4 = ld4(B + (size_t)(k0 + bk) * Nd + bn + bc);
    As[ac + 0][ar] = a4.x; As[ac + 1][ar] = a4.y; As[ac + 2][ar] = a4.z; As[ac + 3][ar] = a4.w;
    st4(&Bs[bk][bc], b4);
    __syncthreads();
    #pragma unroll
    for (int kk = 0; kk < 16; ++kk) {
      float4 av = ld4(&As[kk][tr << 2]);
      float4 bv = ld4(&Bs[kk][tc << 2]);
      acc[0][0] += av.x*bv.x; acc[0][1] += av.x*bv.y; acc[0][2] += av.x*bv.z; acc[0][3] += av.x*bv.w;
      acc[1][0] += av.y*bv.x; acc[1][1] += av.y*bv.y; acc[1][2] += av.y*bv.z; acc[1][3] += av.y*bv.w;
      acc[2][0] += av.z*bv.x; acc[2][1] += av.z*bv.y; acc[2][2] += av.z*bv.z; acc[2][3] += av.z*bv.w;
      acc[3][0] += av.w*bv.x; acc[3][1] += av.w*bv.y; acc[3][2] += av.w*bv.z; acc[3][3] += av.w*bv.w;
    }
    __syncthreads();
  }
  int c0 = bn + (tc << 2);
  #pragma unroll
  for (int a = 0; a < 4; ++a) {
    int r = bm + (tr << 2) + a;
    float4 v = make_float4(acc[a][0], acc[a][1], acc[a][2], acc[a][3]);
    if (MODE == 0) {
      st4(C + (size_t)r * Nd + c0, v);
    } else if (MODE == 1) {
      st4(C + ((((size_t)(c0 >> 5)) << 10) + r) * 32 + (c0 & 31), v);
    } else if (MODE == 2) {
      float4 x4 = ld4(X + (size_t)r * Nd + c0);
      v.x += x4.x; v.y += x4.y; v.z += x4.z; v.w += x4.w;
      st4(C + (size_t)r * Nd + c0, v);
    } else {
      float4 x4 = ld4(X + (size_t)r * Nd + c0);
      v.x = v.x / (1.f + __expf(-v.x)) * x4.x;
      v.y = v.y / (1.f + __expf(-v.y)) * x4.y;
      v.z = v.z / (1.f + __expf(-v.z)) * x4.z;
      v.w = v.w / (1.f + __expf(-v.w)) * x4.w;
      st4(C + (size_t)r * Nd + c0, v);
    }
  }
}

// ---------------- build M = (QK^T/sqrt(32) - w_rel - effw*f_dist)/eps ----------------
__global__ __launch_bounds__(256) void build_M(const float* __restrict__ Qln,
    const float* __restrict__ Kln, const float* __restrict__ wrel,
    const float* __restrict__ xres, const float* __restrict__ wdist,
    const float* __restrict__ ggate, float* __restrict__ M) {
  int jt = blockIdx.x, it = blockIdx.y, h = blockIdx.z;
  int t = threadIdx.x;
  __shared__ float Qs[64][44], Ks[64][44];
  __shared__ float xi[64][4], xj[64][4];
  #pragma unroll
  for (int rep = 0; rep < 2; ++rep) {
    int idx = t + (rep << 8);
    int rr = idx >> 3, dq = (idx & 7) << 2;
    st4(&Qs[rr][dq], ld4(Qln + ((((size_t)h << 10) + (it << 6) + rr) << 5) + dq));
    st4(&Ks[rr][dq], ld4(Kln + ((((size_t)h << 10) + (jt << 6) + rr) << 5) + dq));
  }
  if (t < 64) {
    int gi = (it << 6) + t, gj = (jt << 6) + t;
    xi[t][0] = xres[gi*3]; xi[t][1] = xres[gi*3+1]; xi[t][2] = xres[gi*3+2];
    xj[t][0] = xres[gj*3]; xj[t][1] = xres[gj*3+1]; xj[t][2] = xres[gj*3+2];
  }
  __syncthreads();
  int g = h >> 2;
  float inv_eps = 2.0f / (float)(1 << g);   // 1/eps: {2,1,0.5,0.25}
  float effw = ggate[h] * wdist[h];
  int tr = t >> 4, tc = t & 15;
  float acc[4][4] = {};
  #pragma unroll
  for (int d0 = 0; d0 < 32; d0 += 4) {
    float4 q4[4], k4[4];
    #pragma unroll
    for (int a = 0; a < 4; ++a) q4[a] = ld4(&Qs[(tr << 2) + a][d0]);
    #pragma unroll
    for (int bq = 0; bq < 4; ++bq) k4[bq] = ld4(&Ks[(tc << 2) + bq][d0]);
    #pragma unroll
    for (int a = 0; a < 4; ++a)
      #pragma unroll
      for (int bq = 0; bq < 4; ++bq)
        acc[a][bq] += q4[a].x*k4[bq].x + q4[a].y*k4[bq].y + q4[a].z*k4[bq].z + q4[a].w*k4[bq].w;
  }
  const float is32 = 0.17677669529663687f;  // 1/sqrt(32)
  #pragma unroll
  for (int a = 0; a < 4; ++a) {
    int il = (tr << 2) + a;
    int i = (it << 6) + il;
    float xa0 = xi[il][0], xa1 = xi[il][1], xa2 = xi[il][2];
    size_t base = ((size_t)h << 20) + ((size_t)i << 10) + (jt << 6) + (tc << 2);
    float4 w4 = ld4(wrel + base);
    float out[4];
    #pragma unroll
    for (int bq = 0; bq < 4; ++bq) {
      int jl = (tc << 2) + bq;
      float dx = xa0 - xj[jl][0], dy = xa1 - xj[jl][1], dz = xa2 - xj[jl][2];
      float d2 = dx*dx + dy*dy + dz*dz;
      float dist = sqrtf(fmaxf(d2, 1e-12f));
      float f = dist / (10.0f + dist);
      float wv = (bq==0)?w4.x:(bq==1)?w4.y:(bq==2)?w4.z:w4.w;
      out[bq] = (acc[a][bq] * is32 - wv - effw * f) * inv_eps;
    }
    st4(M + base, make_float4(out[0], out[1], out[2], out[3]));
  }
}

// ---------------- one Sinkhorn iteration: lu update (row LSE) + column partial sums ----------------
// grid (32 row-blocks, 16 heads), 256 thr = 4 waves x 8 rows; lane owns cols {4l+256c}
__global__ __launch_bounds__(256) void sink_iter(const float* __restrict__ M,
    const float* __restrict__ lvb, const float* __restrict__ mu,
    float* __restrict__ lu_out, float* __restrict__ part) {
  int bt = blockIdx.x, h = blockIdx.y;
  int t = threadIdx.x, w = t >> 6, lane = t & 63;
  int g = h >> 2;
  float eps = 0.5f * (float)(1 << g);
  float fac = 1.f / (1.f + eps);
  const float* Mh = M + ((size_t)h << 20);
  float4 lv4[4];
  #pragma unroll
  for (int c = 0; c < 4; ++c) lv4[c] = ((const float4*)(lvb + (h << 10)))[lane + (c << 6)];
  float4 cacc[4];
  #pragma unroll
  for (int c = 0; c < 4; ++c) cacc[c] = make_float4(0.f, 0.f, 0.f, 0.f);
  int ibase = bt * 32 + w * 8;
  for (int k = 0; k < 8; ++k) {
    int i = ibase + k;
    const float4* row = (const float4*)(Mh + ((size_t)i << 10));
    float4 m4[4];
    #pragma unroll
    for (int c = 0; c < 4; ++c) m4[c] = row[lane + (c << 6)];
    float s = 0.f;
    #pragma unroll
    for (int c = 0; c < 4; ++c) {
      s += __expf(m4[c].x + lv4[c].x);
      s += __expf(m4[c].y + lv4[c].y);
      s += __expf(m4[c].z + lv4[c].z);
      s += __expf(m4[c].w + lv4[c].w);
    }
    #pragma unroll
    for (int off = 1; off < 64; off <<= 1) s += __shfl_xor(s, off);
    float lu = fac * (__logf(fmaxf(mu[(h << 10) + i], 1e-8f)) - __logf(s));
    if (lane == 0) lu_out[(h << 10) + i] = lu;
    #pragma unroll
    for (int c = 0; c < 4; ++c) {
      cacc[c].x += __expf(m4[c].x + lu);
      cacc[c].y += __expf(m4[c].y + lu);
      cacc[c].z += __expf(m4[c].z + lu);
      cacc[c].w += __expf(m4[c].w + lu);
    }
  }
  __shared__ float lds[4][1024];
  #pragma unroll
  for (int c = 0; c < 4; ++c) ((float4*)lds[w])[lane + (c << 6)] = cacc[c];
  __syncthreads();
  #pragma unroll
  for (int c = 0; c < 4; ++c) {
    int j = t + (c << 8);
    float v = lds[0][j] + lds[1][j] + lds[2][j] + lds[3][j];
    part[(((size_t)(h << 5) + bt) << 10) + j] = v;
  }
}

// ---------------- finalize: lv = fac*(log(nu) - log(sum partials)) ----------------
__global__ __launch_bounds__(256) void sink_fin(const float* __restrict__ part,
    const float* __restrict__ nu, float* __restrict__ lvb, float* __restrict__ lv_out) {
  int h = blockIdx.x, t = threadIdx.x;
  int g = h >> 2;
  float eps = 0.5f * (float)(1 << g);
  float fac = 1.f / (1.f + eps);
  #pragma unroll
  for (int c = 0; c < 4; ++c) {
    int j = t + (c << 8);
    float s = 0.f;
    for (int b = 0; b < 32; ++b) s += part[(((size_t)(h << 5) + b) << 10) + j];
    float lv = fac * (__logf(fmaxf(nu[(h << 10) + j], 1e-8f)) - __logf(s));
    lvb[(h << 10) + j] = lv;
    if (lv_out) lv_out[(h << 10) + j] = lv;
  }
}

// ---------------- final: T_norm @ [V | x_res], gate, write o_buf (N,D) and xc (H,N,3) ----------------
__global__ __launch_bounds__(256) void attn_out(const float* __restrict__ M,
    const float* __restrict__ lu_g, const float* __restrict__ lv_g,
    const float* __restrict__ V, const float* __restrict__ G,
    const float* __restrict__ xres, float* __restrict__ o_buf, float* __restrict__ xc) {
  int bt = blockIdx.x, h = blockIdx.y;
  int t = threadIdx.x;
  __shared__ float Ts[64][66];
  __shared__ float Vs[64][40];
  __shared__ float Xs[64][4];
  __shared__ float lv_s[1024];
  __shared__ float lu_s[64];
  __shared__ float rs_s[64];
  ((float4*)lv_s)[t] = ((const float4*)(lv_g + (h << 10)))[t];
  if (t < 64) lu_s[t] = lu_g[(h << 10) + bt * 64 + t];
  int i0 = bt * 64;
  const size_t Mh = ((size_t)h << 20);
  int rg = t >> 3, cg = t & 7;
  int rg2 = rg << 1;
  int xr = t & 63, xcc = t >> 6;   // role for t < 192
  float accO0[4] = {0,0,0,0}, accO1[4] = {0,0,0,0};
  float accX = 0.f, rs0 = 0.f, rs1 = 0.f;
  for (int jt = 0; jt < 16; ++jt) {
    __syncthreads();
    #pragma unroll
    for (int rep = 0; rep < 4; ++rep) {
      int r = (t >> 4) + (rep << 4);
      int jj0 = (t & 15) << 2;
      float4 m4 = ld4(M + Mh + (((size_t)(i0 + r)) << 10) + (jt << 6) + jj0);
      float lur = lu_s[r];
      Ts[jj0 + 0][r] = __expf(m4.x + lur + lv_s[(jt << 6) + jj0 + 0]);
      Ts[jj0 + 1][r] = __expf(m4.y + lur + lv_s[(jt << 6) + jj0 + 1]);
      Ts[jj0 + 2][r] = __expf(m4.z + lur + lv_s[(jt << 6) + jj0 + 2]);
      Ts[jj0 + 3][r] = __expf(m4.w + lur + lv_s[(jt << 6) + jj0 + 3]);
    }
    #pragma unroll
    for (int rep = 0; rep < 2; ++rep) {
      int idx = t + (rep << 8);
      int vr = idx >> 3, dq = (idx & 7) << 2;
      st4(&Vs[vr][dq], ld4(V + ((((size_t)h << 10) + (jt << 6) + vr) << 5) + dq));
    }
    if (t < 64) {
      int j = (jt << 6) + t;
      Xs[t][0] = xres[j*3]; Xs[t][1] = xres[j*3+1]; Xs[t][2] = xres[j*3+2];
    }
    __syncthreads();
    #pragma unroll 4
    for (int jj = 0; jj < 64; ++jj) {
      float t0 = Ts[jj][rg2];
      float t1 = Ts[jj][rg2 + 1];
      float4 v4 = ld4(&Vs[jj][cg << 2]);
      accO0[0] += t0*v4.x; accO0[1] += t0*v4.y; accO0[2] += t0*v4.z; accO0[3] += t0*v4.w;
      accO1[0] += t1*v4.x; accO1[1] += t1*v4.y; accO1[2] += t1*v4.z; accO1[3] += t1*v4.w;
      if (cg == 0) { rs0 += t0; rs1 += t1; }
      if (t < 192) accX += Ts[jj][xr] * Xs[jj][xcc];
    }
  }
  if (cg == 0) { rs_s[rg2] = rs0; rs_s[rg2 + 1] = rs1; }
  __syncthreads();
  {
    float inv0 = 1.f / (rs_s[rg2] + 1e-8f);
    float inv1 = 1.f / (rs_s[rg2 + 1] + 1e-8f);
    int ia = i0 + rg2, ib = ia + 1;
    size_t oa = ((size_t)ia << 9) + (h << 5) + (cg << 2);
    size_t ob = ((size_t)ib << 9) + (h << 5) + (cg << 2);
    float4 g0 = ld4(G + oa), g1 = ld4(G + ob);
    float4 o0, o1;
    o0.x = accO0[0]*inv0 / (1.f + __expf(-g0.x));
    o0.y = accO0[1]*inv0 / (1.f + __expf(-g0.y));
    o0.z = accO0[2]*inv0 / (1.f + __expf(-g0.z));
    o0.w = accO0[3]*inv0 / (1.f + __expf(-g0.w));
    o1.x = accO1[0]*inv1 / (1.f + __expf(-g1.x));
    o1.y = accO1[1]*inv1 / (1.f + __expf(-g1.y));
    o1.z = accO1[2]*inv1 / (1.f + __expf(-g1.z));
    o1.w = accO1[3]*inv1 / (1.f + __expf(-g1.w));
    st4(o_buf + oa, o0);
    st4(o_buf + ob, o1);
  }
  if (t < 192) {
    float inv = 1.f / (rs_s[xr] + 1e-8f);
    xc[((size_t)((h << 10) + i0 + xr)) * 3 + xcc] = accX * inv;
  }
}

// ---------------- x_res update ----------------
__global__ void x_update(const float* __restrict__ xres, const float* __restrict__ xc,
    const float* __restrict__ gamma, float* __restrict__ xout) {
  int idx = blockIdx.x * 256 + threadIdx.x;
  if (idx >= 3072) return;
  float x = xres[idx];
  float s = x;
  #pragma unroll
  for (int hh = 0; hh < 16; ++hh) s += gamma[hh] * (x - xc[(size_t)hh * 3072 + idx]);
  xout[idx] = s;
}

extern "C" void kernel_launch(void* const* d_in, const int* in_sizes, int n_in,
                              void* d_out, int out_size, void* d_ws, size_t ws_size,
                              hipStream_t stream) {
  const float* h_in    = (const float*)d_in[0];
  const float* x_res   = (const float*)d_in[1];
  const float* mu      = (const float*)d_in[2];
  const float* nu      = (const float*)d_in[3];
  const float* lv_prev = (const float*)d_in[5];
  const float* wrel    = (const float*)d_in[6];
  const float* wdist   = (const float*)d_in[7];
  const float* ggate   = (const float*)d_in[9];
  const float* lnaw    = (const float*)d_in[10];
  const float* lnab    = (const float*)d_in[11];
  const float* Wq      = (const float*)d_in[12];
  const float* Wk      = (const float*)d_in[13];
  const float* Wv      = (const float*)d_in[14];
  const float* Wg      = (const float*)d_in[15];
  const float* Wo      = (const float*)d_in[16];
  const float* gamma   = (const float*)d_in[17];
  const float* lnfw    = (const float*)d_in[18];
  const float* lnfb    = (const float*)d_in[19];
  const float* W1      = (const float*)d_in[20];
  const float* W3      = (const float*)d_in[21];
  const float* W2      = (const float*)d_in[22];

  float* out = (float*)d_out;
  float* OUT_H  = out;
  float* OUT_X  = out + 524288;
  float* OUT_LU = out + 527360;
  float* OUT_LV = out + 543744;

  if (ws_size < (size_t)19988480 * sizeof(float)) return;
  float* ws  = (float*)d_ws;
  float* h_n  = ws;                  // 524288
  float* Qb   = ws + 524288;         // 524288 (H,N,32)
  float* Kb   = ws + 1048576;        // 524288
  float* Vb   = ws + 1572864;        // 524288
  float* Gb   = ws + 2097152;        // 524288 (N,D)
  float* Mb   = ws + 2621440;        // 16777216
  float* part = ws + 19398656;       // 524288 (H,32,N)
  float* lvb  = ws + 19922944;       // 16384
  float* xcb  = ws + 19939328;       // 49152
  float* ffb  = h_n;                 // reuse (dead after QKVG gemms)
  float* o_buf = Qb;                 // reuse (dead after build_M)
  float* h2   = Kb;                  // reuse (dead after build_M)
  float* Bb   = Mb;                  // reuse (M dead after attn_out)
  float* ABb  = Mb + 2097152;

  ln_rows<<<NTOK, 256, 0, stream>>>(h_in, lnaw, lnab, h_n);
  dim3 g8(8, 16);
  gemm64<1><<<g8, 256, 0, stream>>>(h_n, Wq, Qb, nullptr, 512, 512);
  gemm64<1><<<g8, 256, 0, stream>>>(h_n, Wk, Kb, nullptr, 512, 512);
  gemm64<1><<<g8, 256, 0, stream>>>(h_n, Wv, Vb, nullptr, 512, 512);
  gemm64<0><<<g8, 256, 0, stream>>>(h_n, Wg, Gb, nullptr, 512, 512);
  qk_ln<<<dim3(2048, 2), 256, 0, stream>>>(Qb, Kb);
  build_M<<<dim3(16, 16, 16), 256, 0, stream>>>(Qb, Kb, wrel, x_res, wdist, ggate, Mb);
  hipMemcpyAsync(lvb, lv_prev, 16384 * sizeof(float), hipMemcpyDeviceToDevice, stream);
  for (int it = 0; it < 20; ++it) {
    sink_iter<<<dim3(32, 16), 256, 0, stream>>>(Mb, lvb, mu, OUT_LU, part);
    sink_fin<<<16, 256, 0, stream>>>(part, nu, lvb, (it == 19) ? OUT_LV : nullptr);
  }
  attn_out<<<dim3(16, 16), 256, 0, stream>>>(Mb, OUT_LU, lvb, Vb, Gb, x_res, o_buf, xcb);
  x_update<<<12, 256, 0, stream>>>(x_res, xcb, gamma, OUT_X);
  gemm64<2><<<g8, 256, 0, stream>>>(o_buf, Wo, h2, h_in, 512, 512);
  ln_rows<<<NTOK, 256, 0, stream>>>(h2, lnfw, lnfb, ffb);
  dim3 g32(32, 16);
  gemm64<0><<<g32, 256, 0, stream>>>(ffb, W3, Bb, nullptr, 512, 2048);
  gemm64<3><<<g32, 256, 0, stream>>>(ffb, W1, ABb, Bb, 512, 2048);
  gemm64<2><<<g8, 256, 0, stream>>>(ABb, W2, OUT_H, h2, 2048, 512);
}

// Round 3
// 608.980 us; speedup vs baseline: 1.4842x; 1.4842x over previous
//
#include <hip/hip_runtime.h>
#include <math.h>

#define NTOK 1024
#define DDIM 512

using short8 = __attribute__((ext_vector_type(8))) short;
using f32x4  = __attribute__((ext_vector_type(4))) float;

__device__ __forceinline__ float4 ld4(const float* p){ return *(const float4*)p; }
__device__ __forceinline__ void st4(float* p, float4 v){ *(float4*)p = v; }
__device__ __forceinline__ unsigned short bf16r(float x) {
  unsigned int u = __float_as_uint(x);
  u += 0x7fffu + ((u >> 16) & 1u);
  return (unsigned short)(u >> 16);
}
__device__ __forceinline__ float bf16f(unsigned short h) {
  return __uint_as_float(((unsigned int)h) << 16);
}
__device__ __forceinline__ f32x4 mfma16(short8 a, short8 b, f32x4 c) {
  return __builtin_amdgcn_mfma_f32_16x16x32_bf16(a, b, c, 0, 0, 0);
}

// ---------------- LayerNorm over D=512 with affine, fp32 out ----------------
__global__ __launch_bounds__(256) void ln_rows(const float* __restrict__ x,
    const float* __restrict__ w, const float* __restrict__ b, float* __restrict__ y) {
  int row = blockIdx.x, t = threadIdx.x;
  const float* xr = x + ((size_t)row << 9);
  float v0 = xr[t], v1 = xr[t + 256];
  float s = v0 + v1, q = v0*v0 + v1*v1;
  #pragma unroll
  for (int off = 1; off < 64; off <<= 1) { s += __shfl_xor(s, off); q += __shfl_xor(q, off); }
  __shared__ float ls[4], lq[4], mb[2];
  int wv = t >> 6;
  if ((t & 63) == 0) { ls[wv] = s; lq[wv] = q; }
  __syncthreads();
  if (t == 0) {
    float S = ls[0]+ls[1]+ls[2]+ls[3];
    float Q = lq[0]+lq[1]+lq[2]+lq[3];
    float m = S * (1.f/512.f);
    float var = Q * (1.f/512.f) - m*m;
    mb[0] = m; mb[1] = 1.f / sqrtf(var + 1e-5f);
  }
  __syncthreads();
  float m = mb[0], inv = mb[1];
  float* yr = y + ((size_t)row << 9);
  yr[t]       = (v0 - m) * inv * w[t] + b[t];
  yr[t + 256] = (v1 - m) * inv * w[t + 256] + b[t + 256];
}

// ------- convert + transpose + hi/lo split: src (K x N) fp32 -> dst hi (N x K), lo (N x K) bf16 -------
__global__ __launch_bounds__(256) void convT(const float* __restrict__ src,
    unsigned short* __restrict__ dst, int K, int N) {
  __shared__ unsigned short Th[64][68];
  __shared__ unsigned short Tl[64][68];
  int nt = blockIdx.x << 6, kt = blockIdx.y << 6;
  int t = threadIdx.x;
  int r = t >> 4, c4 = (t & 15) << 2;
  #pragma unroll
  for (int p = 0; p < 4; ++p) {
    int kk = r + (p << 4);
    float4 v = ld4(src + (size_t)(kt + kk) * N + nt + c4);
    float vv[4] = {v.x, v.y, v.z, v.w};
    #pragma unroll
    for (int i = 0; i < 4; ++i) {
      unsigned short h = bf16r(vv[i]);
      Th[c4 + i][kk] = h;
      Tl[c4 + i][kk] = bf16r(vv[i] - bf16f(h));
    }
  }
  __syncthreads();
  size_t loff = (size_t)N * K;
  #pragma unroll
  for (int p = 0; p < 4; ++p) {
    int nn = r + (p << 4);
    ushort4 oh, ol;
    oh.x = Th[nn][c4]; oh.y = Th[nn][c4+1]; oh.z = Th[nn][c4+2]; oh.w = Th[nn][c4+3];
    ol.x = Tl[nn][c4]; ol.y = Tl[nn][c4+1]; ol.z = Tl[nn][c4+2]; ol.w = Tl[nn][c4+3];
    *(ushort4*)(dst + (size_t)(nt + nn) * K + kt + c4) = oh;
    *(ushort4*)(dst + loff + (size_t)(nt + nn) * K + kt + c4) = ol;
  }
}

// ---------------- split-precision bf16 MFMA GEMM ----------------
// A (M x K) fp32, W pre-split: hi (N x K) bf16 at W, lo at W + N*K.
// acc = Ah*Wh + Al*Wh + Ah*Wl  (~fp32 accurate)
// MODE 0: z selects weight/dst; z<3 scatter fp32 to (H,N,32); z==3 plain fp32 (N,Nd)
// MODE 1: plain fp32 C[m*Nd+n]; z selects (W,C) pair; optional split-K window kwin
struct P4 {
  const unsigned short *W0, *W1, *W2, *W3;
  float *C0, *C1, *C2, *C3;
};
template<int MODE>
__global__ __launch_bounds__(256) void gemm_mfma(const float* __restrict__ A,
    P4 p, int Kd, int Nd, int kwin) {
  __shared__ unsigned short Ash[64][72];
  __shared__ unsigned short Asl[64][72];
  __shared__ unsigned short Bsh[64][72];
  __shared__ unsigned short Bsl[64][72];
  int t = threadIdx.x;
  int z = blockIdx.z;
  const unsigned short* W = (z==0)?p.W0:(z==1)?p.W1:(z==2)?p.W2:p.W3;
  float* C = (z==0)?p.C0:(z==1)?p.C1:(z==2)?p.C2:p.C3;
  const unsigned short* Wl = W + (size_t)Nd * Kd;
  int bm = blockIdx.y << 6, bn = blockIdx.x << 6;
  int wid = t >> 6, lane = t & 63;
  int wm = wid >> 1, wn = wid & 1;
  int lr = lane & 15, lk = lane >> 4;
  int r0 = t >> 3, ks = (t & 7) << 3;
  int kbeg = kwin ? z * kwin : 0;
  int kend = kwin ? kbeg + kwin : Kd;
  f32x4 acc[2][2];
  #pragma unroll
  for (int i = 0; i < 2; ++i)
    #pragma unroll
    for (int j = 0; j < 2; ++j)
      #pragma unroll
      for (int r = 0; r < 4; ++r) acc[i][j][r] = 0.f;
  for (int k0 = kbeg; k0 < kend; k0 += 64) {
    float4 a00 = ld4(A + (size_t)(bm + r0) * Kd + k0 + ks);
    float4 a01 = ld4(A + (size_t)(bm + r0) * Kd + k0 + ks + 4);
    float4 a10 = ld4(A + (size_t)(bm + r0 + 32) * Kd + k0 + ks);
    float4 a11 = ld4(A + (size_t)(bm + r0 + 32) * Kd + k0 + ks + 4);
    uint4 b0h = *(const uint4*)(W  + (size_t)(bn + r0) * Kd + k0 + ks);
    uint4 b1h = *(const uint4*)(W  + (size_t)(bn + r0 + 32) * Kd + k0 + ks);
    uint4 b0l = *(const uint4*)(Wl + (size_t)(bn + r0) * Kd + k0 + ks);
    uint4 b1l = *(const uint4*)(Wl + (size_t)(bn + r0 + 32) * Kd + k0 + ks);
    __syncthreads();
    {
      float va[8] = {a00.x,a00.y,a00.z,a00.w,a01.x,a01.y,a01.z,a01.w};
      short8 h8, l8;
      #pragma unroll
      for (int i = 0; i < 8; ++i) {
        unsigned short h = bf16r(va[i]);
        h8[i] = (short)h; l8[i] = (short)bf16r(va[i] - bf16f(h));
      }
      *(short8*)&Ash[r0][ks] = h8;
      *(short8*)&Asl[r0][ks] = l8;
    }
    {
      float va[8] = {a10.x,a10.y,a10.z,a10.w,a11.x,a11.y,a11.z,a11.w};
      short8 h8, l8;
      #pragma unroll
      for (int i = 0; i < 8; ++i) {
        unsigned short h = bf16r(va[i]);
        h8[i] = (short)h; l8[i] = (short)bf16r(va[i] - bf16f(h));
      }
      *(short8*)&Ash[r0 + 32][ks] = h8;
      *(short8*)&Asl[r0 + 32][ks] = l8;
    }
    *(uint4*)&Bsh[r0][ks] = b0h;
    *(uint4*)&Bsh[r0 + 32][ks] = b1h;
    *(uint4*)&Bsl[r0][ks] = b0l;
    *(uint4*)&Bsl[r0 + 32][ks] = b1l;
    __syncthreads();
    #pragma unroll
    for (int s = 0; s < 2; ++s) {
      short8 ah0 = *(const short8*)&Ash[wm*32 + lr][s*32 + lk*8];
      short8 ah1 = *(const short8*)&Ash[wm*32 + 16 + lr][s*32 + lk*8];
      short8 al0 = *(const short8*)&Asl[wm*32 + lr][s*32 + lk*8];
      short8 al1 = *(const short8*)&Asl[wm*32 + 16 + lr][s*32 + lk*8];
      short8 bh0 = *(const short8*)&Bsh[wn*32 + lr][s*32 + lk*8];
      short8 bh1 = *(const short8*)&Bsh[wn*32 + 16 + lr][s*32 + lk*8];
      short8 bl0 = *(const short8*)&Bsl[wn*32 + lr][s*32 + lk*8];
      short8 bl1 = *(const short8*)&Bsl[wn*32 + 16 + lr][s*32 + lk*8];
      acc[0][0] = mfma16(ah0, bh0, acc[0][0]);
      acc[0][1] = mfma16(ah0, bh1, acc[0][1]);
      acc[1][0] = mfma16(ah1, bh0, acc[1][0]);
      acc[1][1] = mfma16(ah1, bh1, acc[1][1]);
      acc[0][0] = mfma16(al0, bh0, acc[0][0]);
      acc[0][1] = mfma16(al0, bh1, acc[0][1]);
      acc[1][0] = mfma16(al1, bh0, acc[1][0]);
      acc[1][1] = mfma16(al1, bh1, acc[1][1]);
      acc[0][0] = mfma16(ah0, bl0, acc[0][0]);
      acc[0][1] = mfma16(ah0, bl1, acc[0][1]);
      acc[1][0] = mfma16(ah1, bl0, acc[1][0]);
      acc[1][1] = mfma16(ah1, bl1, acc[1][1]);
    }
  }
  #pragma unroll
  for (int fm = 0; fm < 2; ++fm)
    #pragma unroll
    for (int fn = 0; fn < 2; ++fn) {
      int n = bn + wn*32 + fn*16 + lr;
      #pragma unroll
      for (int r = 0; r < 4; ++r) {
        int m = bm + wm*32 + fm*16 + lk*4 + r;
        float v = acc[fm][fn][r];
        if (MODE == 0) {
          if (z < 3) C[(((size_t)(n >> 5) << 10) + m) * 32 + (n & 31)] = v;
          else       C[(size_t)m * Nd + n] = v;
        } else {
          C[(size_t)m * Nd + n] = v;
        }
      }
    }
}

// ---------------- per-head LN over DH=32 (no affine), in place; Q and K ----------------
__global__ __launch_bounds__(256) void qk_ln(float* __restrict__ Q, float* __restrict__ K) {
  float* P = blockIdx.y ? K : Q;
  int t = threadIdx.x;
  int row = blockIdx.x * 8 + (t >> 5);
  int l = t & 31;
  float* p = P + ((size_t)row << 5);
  float x = p[l];
  float s = x, q = x*x;
  #pragma unroll
  for (int off = 16; off; off >>= 1) { s += __shfl_xor(s, off, 32); q += __shfl_xor(q, off, 32); }
  float m = s * (1.f/32.f);
  float var = q * (1.f/32.f) - m*m;
  float inv = 1.f / sqrtf(var + 1e-5f);
  p[l] = (x - m) * inv;
}

// ---------------- build M = (QK^T/sqrt(32) - w_rel - effw*f_dist)/eps ----------------
__global__ __launch_bounds__(256) void build_M(const float* __restrict__ Qln,
    const float* __restrict__ Kln, const float* __restrict__ wrel,
    const float* __restrict__ xres, const float* __restrict__ wdist,
    const float* __restrict__ ggate, float* __restrict__ M) {
  int jt = blockIdx.x, it = blockIdx.y, h = blockIdx.z;
  int t = threadIdx.x;
  __shared__ float Qs[64][44], Ks[64][44];
  __shared__ float xi[64][4], xj[64][4];
  #pragma unroll
  for (int rep = 0; rep < 2; ++rep) {
    int idx = t + (rep << 8);
    int rr = idx >> 3, dq = (idx & 7) << 2;
    st4(&Qs[rr][dq], ld4(Qln + ((((size_t)h << 10) + (it << 6) + rr) << 5) + dq));
    st4(&Ks[rr][dq], ld4(Kln + ((((size_t)h << 10) + (jt << 6) + rr) << 5) + dq));
  }
  if (t < 64) {
    int gi = (it << 6) + t, gj = (jt << 6) + t;
    xi[t][0] = xres[gi*3]; xi[t][1] = xres[gi*3+1]; xi[t][2] = xres[gi*3+2];
    xj[t][0] = xres[gj*3]; xj[t][1] = xres[gj*3+1]; xj[t][2] = xres[gj*3+2];
  }
  __syncthreads();
  int g = h >> 2;
  float inv_eps = 2.0f / (float)(1 << g);
  float effw = ggate[h] * wdist[h];
  int tr = t >> 4, tc = t & 15;
  float acc[4][4] = {};
  #pragma unroll
  for (int d0 = 0; d0 < 32; d0 += 4) {
    float4 q4[4], k4[4];
    #pragma unroll
    for (int a = 0; a < 4; ++a) q4[a] = ld4(&Qs[(tr << 2) + a][d0]);
    #pragma unroll
    for (int bq = 0; bq < 4; ++bq) k4[bq] = ld4(&Ks[(tc << 2) + bq][d0]);
    #pragma unroll
    for (int a = 0; a < 4; ++a)
      #pragma unroll
      for (int bq = 0; bq < 4; ++bq)
        acc[a][bq] += q4[a].x*k4[bq].x + q4[a].y*k4[bq].y + q4[a].z*k4[bq].z + q4[a].w*k4[bq].w;
  }
  const float is32 = 0.17677669529663687f;
  #pragma unroll
  for (int a = 0; a < 4; ++a) {
    int il = (tr << 2) + a;
    int i = (it << 6) + il;
    float xa0 = xi[il][0], xa1 = xi[il][1], xa2 = xi[il][2];
    size_t base = ((size_t)h << 20) + ((size_t)i << 10) + (jt << 6) + (tc << 2);
    float4 w4 = ld4(wrel + base);
    float out[4];
    #pragma unroll
    for (int bq = 0; bq < 4; ++bq) {
      int jl = (tc << 2) + bq;
      float dx = xa0 - xj[jl][0], dy = xa1 - xj[jl][1], dz = xa2 - xj[jl][2];
      float d2 = dx*dx + dy*dy + dz*dz;
      float dist = sqrtf(fmaxf(d2, 1e-12f));
      float f = dist / (10.0f + dist);
      float wv = (bq==0)?w4.x:(bq==1)?w4.y:(bq==2)?w4.z:w4.w;
      out[bq] = (acc[a][bq] * is32 - wv - effw * f) * inv_eps;
    }
    st4(M + base, make_float4(out[0], out[1], out[2], out[3]));
  }
}

// ---------------- one Sinkhorn iteration: lu update (row LSE) + column partial sums ----------------
__global__ __launch_bounds__(256) void sink_iter(const float* __restrict__ M,
    const float* __restrict__ lvb, const float* __restrict__ mu,
    float* __restrict__ lu_out, float* __restrict__ part) {
  int bt = blockIdx.x, h = blockIdx.y;
  int t = threadIdx.x, w = t >> 6, lane = t & 63;
  int g = h >> 2;
  float eps = 0.5f * (float)(1 << g);
  float fac = 1.f / (1.f + eps);
  const float* Mh = M + ((size_t)h << 20);
  float4 lv4[4];
  #pragma unroll
  for (int c = 0; c < 4; ++c) lv4[c] = ((const float4*)(lvb + (h << 10)))[lane + (c << 6)];
  float4 cacc[4];
  #pragma unroll
  for (int c = 0; c < 4; ++c) cacc[c] = make_float4(0.f, 0.f, 0.f, 0.f);
  int ibase = bt * 32 + w * 8;
  for (int k = 0; k < 8; ++k) {
    int i = ibase + k;
    const float4* row = (const float4*)(Mh + ((size_t)i << 10));
    float4 m4[4];
    #pragma unroll
    for (int c = 0; c < 4; ++c) m4[c] = row[lane + (c << 6)];
    float s = 0.f;
    #pragma unroll
    for (int c = 0; c < 4; ++c) {
      s += __expf(m4[c].x + lv4[c].x);
      s += __expf(m4[c].y + lv4[c].y);
      s += __expf(m4[c].z + lv4[c].z);
      s += __expf(m4[c].w + lv4[c].w);
    }
    #pragma unroll
    for (int off = 1; off < 64; off <<= 1) s += __shfl_xor(s, off);
    float lu = fac * (__logf(fmaxf(mu[(h << 10) + i], 1e-8f)) - __logf(s));
    if (lane == 0) lu_out[(h << 10) + i] = lu;
    #pragma unroll
    for (int c = 0; c < 4; ++c) {
      cacc[c].x += __expf(m4[c].x + lu);
      cacc[c].y += __expf(m4[c].y + lu);
      cacc[c].z += __expf(m4[c].z + lu);
      cacc[c].w += __expf(m4[c].w + lu);
    }
  }
  __shared__ float lds[4][1024];
  #pragma unroll
  for (int c = 0; c < 4; ++c) ((float4*)lds[w])[lane + (c << 6)] = cacc[c];
  __syncthreads();
  #pragma unroll
  for (int c = 0; c < 4; ++c) {
    int j = t + (c << 8);
    float v = lds[0][j] + lds[1][j] + lds[2][j] + lds[3][j];
    part[(((size_t)(h << 5) + bt) << 10) + j] = v;
  }
}

// ---------------- finalize: lv = fac*(log(nu) - log(sum partials)) ----------------
__global__ __launch_bounds__(256) void sink_fin(const float* __restrict__ part,
    const float* __restrict__ nu, float* __restrict__ lvb, float* __restrict__ lv_out) {
  int h = blockIdx.x, t = threadIdx.x;
  int g = h >> 2;
  float eps = 0.5f * (float)(1 << g);
  float fac = 1.f / (1.f + eps);
  #pragma unroll
  for (int c = 0; c < 4; ++c) {
    int j = t + (c << 8);
    float s = 0.f;
    for (int b = 0; b < 32; ++b) s += part[(((size_t)(h << 5) + b) << 10) + j];
    float lv = fac * (__logf(fmaxf(nu[(h << 10) + j], 1e-8f)) - __logf(s));
    lvb[(h << 10) + j] = lv;
    if (lv_out) lv_out[(h << 10) + j] = lv;
  }
}

// ---------------- final: T_norm @ [V | x_res], gate, write o_buf fp32 (N,D) and xc (H,N,3) ----------------
__global__ __launch_bounds__(256) void attn_out(const float* __restrict__ M,
    const float* __restrict__ lu_g, const float* __restrict__ lv_g,
    const float* __restrict__ V, const float* __restrict__ G,
    const float* __restrict__ xres, float* __restrict__ o_buf, float* __restrict__ xc) {
  int bt = blockIdx.x, h = blockIdx.y;
  int t = threadIdx.x;
  __shared__ float Ts[64][66];
  __shared__ float Vs[64][40];
  __shared__ float Xs[64][4];
  __shared__ float lv_s[1024];
  __shared__ float lu_s[64];
  __shared__ float rs_s[64];
  ((float4*)lv_s)[t] = ((const float4*)(lv_g + (h << 10)))[t];
  if (t < 64) lu_s[t] = lu_g[(h << 10) + bt * 64 + t];
  int i0 = bt * 64;
  const size_t Mh = ((size_t)h << 20);
  int rg = t >> 3, cg = t & 7;
  int rg2 = rg << 1;
  int xr = t & 63, xcc = t >> 6;
  float accO0[4] = {0,0,0,0}, accO1[4] = {0,0,0,0};
  float accX = 0.f, rs0 = 0.f, rs1 = 0.f;
  for (int jt = 0; jt < 16; ++jt) {
    __syncthreads();
    #pragma unroll
    for (int rep = 0; rep < 4; ++rep) {
      int r = (t >> 4) + (rep << 4);
      int jj0 = (t & 15) << 2;
      float4 m4 = ld4(M + Mh + (((size_t)(i0 + r)) << 10) + (jt << 6) + jj0);
      float lur = lu_s[r];
      Ts[jj0 + 0][r] = __expf(m4.x + lur + lv_s[(jt << 6) + jj0 + 0]);
      Ts[jj0 + 1][r] = __expf(m4.y + lur + lv_s[(jt << 6) + jj0 + 1]);
      Ts[jj0 + 2][r] = __expf(m4.z + lur + lv_s[(jt << 6) + jj0 + 2]);
      Ts[jj0 + 3][r] = __expf(m4.w + lur + lv_s[(jt << 6) + jj0 + 3]);
    }
    #pragma unroll
    for (int rep = 0; rep < 2; ++rep) {
      int idx = t + (rep << 8);
      int vr = idx >> 3, dq = (idx & 7) << 2;
      st4(&Vs[vr][dq], ld4(V + ((((size_t)h << 10) + (jt << 6) + vr) << 5) + dq));
    }
    if (t < 64) {
      int j = (jt << 6) + t;
      Xs[t][0] = xres[j*3]; Xs[t][1] = xres[j*3+1]; Xs[t][2] = xres[j*3+2];
    }
    __syncthreads();
    #pragma unroll 4
    for (int jj = 0; jj < 64; ++jj) {
      float t0 = Ts[jj][rg2];
      float t1 = Ts[jj][rg2 + 1];
      float4 v4 = ld4(&Vs[jj][cg << 2]);
      accO0[0] += t0*v4.x; accO0[1] += t0*v4.y; accO0[2] += t0*v4.z; accO0[3] += t0*v4.w;
      accO1[0] += t1*v4.x; accO1[1] += t1*v4.y; accO1[2] += t1*v4.z; accO1[3] += t1*v4.w;
      if (cg == 0) { rs0 += t0; rs1 += t1; }
      if (t < 192) accX += Ts[jj][xr] * Xs[jj][xcc];
    }
  }
  if (cg == 0) { rs_s[rg2] = rs0; rs_s[rg2 + 1] = rs1; }
  __syncthreads();
  {
    float inv0 = 1.f / (rs_s[rg2] + 1e-8f);
    float inv1 = 1.f / (rs_s[rg2 + 1] + 1e-8f);
    int ia = i0 + rg2, ib = ia + 1;
    size_t oa = ((size_t)ia << 9) + (h << 5) + (cg << 2);
    size_t ob = ((size_t)ib << 9) + (h << 5) + (cg << 2);
    float4 g0 = ld4(G + oa), g1 = ld4(G + ob);
    float4 o0, o1;
    o0.x = accO0[0]*inv0 / (1.f + __expf(-g0.x));
    o0.y = accO0[1]*inv0 / (1.f + __expf(-g0.y));
    o0.z = accO0[2]*inv0 / (1.f + __expf(-g0.z));
    o0.w = accO0[3]*inv0 / (1.f + __expf(-g0.w));
    o1.x = accO1[0]*inv1 / (1.f + __expf(-g1.x));
    o1.y = accO1[1]*inv1 / (1.f + __expf(-g1.y));
    o1.z = accO1[2]*inv1 / (1.f + __expf(-g1.z));
    o1.w = accO1[3]*inv1 / (1.f + __expf(-g1.w));
    st4(o_buf + oa, o0);
    st4(o_buf + ob, o1);
  }
  if (t < 192) {
    float inv = 1.f / (rs_s[xr] + 1e-8f);
    xc[((size_t)((h << 10) + i0 + xr)) * 3 + xcc] = accX * inv;
  }
}

// ---------------- x_res update ----------------
__global__ void x_update(const float* __restrict__ xres, const float* __restrict__ xc,
    const float* __restrict__ gamma, float* __restrict__ xout) {
  int idx = blockIdx.x * 256 + threadIdx.x;
  if (idx >= 3072) return;
  float x = xres[idx];
  float s = x;
  #pragma unroll
  for (int hh = 0; hh < 16; ++hh) s += gamma[hh] * (x - xc[(size_t)hh * 3072 + idx]);
  xout[idx] = s;
}

// ---------------- silu(P1)*P3 -> fp32 ----------------
__global__ __launch_bounds__(256) void silu_mul(const float* __restrict__ P1,
    const float* __restrict__ P3, float* __restrict__ AB) {
  int i = (blockIdx.x * 256 + threadIdx.x) << 2;
  float4 a = ld4(P1 + i), b = ld4(P3 + i);
  float4 o;
  o.x = a.x / (1.f + __expf(-a.x)) * b.x;
  o.y = a.y / (1.f + __expf(-a.y)) * b.y;
  o.z = a.z / (1.f + __expf(-a.z)) * b.z;
  o.w = a.w / (1.f + __expf(-a.w)) * b.w;
  st4(AB + i, o);
}

// ---------------- o = a + b + c ----------------
__global__ __launch_bounds__(256) void add3(const float* __restrict__ a,
    const float* __restrict__ b, const float* __restrict__ c, float* __restrict__ o) {
  int i = (blockIdx.x * 256 + threadIdx.x) << 2;
  float4 va = ld4(a + i), vb = ld4(b + i), vc = ld4(c + i);
  st4(o + i, make_float4(va.x+vb.x+vc.x, va.y+vb.y+vc.y, va.z+vb.z+vc.z, va.w+vb.w+vc.w));
}

extern "C" void kernel_launch(void* const* d_in, const int* in_sizes, int n_in,
                              void* d_out, int out_size, void* d_ws, size_t ws_size,
                              hipStream_t stream) {
  const float* h_in    = (const float*)d_in[0];
  const float* x_res   = (const float*)d_in[1];
  const float* mu      = (const float*)d_in[2];
  const float* nu      = (const float*)d_in[3];
  const float* lv_prev = (const float*)d_in[5];
  const float* wrel    = (const float*)d_in[6];
  const float* wdist   = (const float*)d_in[7];
  const float* ggate   = (const float*)d_in[9];
  const float* lnaw    = (const float*)d_in[10];
  const float* lnab    = (const float*)d_in[11];
  const float* Wq      = (const float*)d_in[12];
  const float* Wk      = (const float*)d_in[13];
  const float* Wv      = (const float*)d_in[14];
  const float* Wg      = (const float*)d_in[15];
  const float* Wo      = (const float*)d_in[16];
  const float* gamma   = (const float*)d_in[17];
  const float* lnfw    = (const float*)d_in[18];
  const float* lnfb    = (const float*)d_in[19];
  const float* W1      = (const float*)d_in[20];
  const float* W3      = (const float*)d_in[21];
  const float* W2      = (const float*)d_in[22];

  float* out = (float*)d_out;
  float* OUT_H  = out;
  float* OUT_X  = out + 524288;
  float* OUT_LU = out + 527360;
  float* OUT_LV = out + 543744;

  if (ws_size < (size_t)19464192 * sizeof(float)) return;
  float* ws   = (float*)d_ws;
  float* Qb   = ws;                    // 524288 (H,N,32) f32
  float* Kb   = ws + 524288;           // 524288
  float* Vb   = ws + 1048576;          // 524288
  float* Gb   = ws + 1572864;          // 524288 (N,D) f32
  float* Mb   = ws + 2097152;          // 16777216 f32
  float* part = ws + 18874368;         // 524288 (H,32,N)
  float* lvb  = ws + 19398656;         // 16384
  float* xcb  = ws + 19415040;         // 49152
  // Phase-A overlays inside Mb (dead before build_M writes M):
  float* h_n = Mb;                                        // 1024x512 f32
  unsigned short* WqT = (unsigned short*)(Mb + 524288);   // 512x512 hi+lo bf16 = 262144 f32 each
  unsigned short* WkT = (unsigned short*)(Mb + 786432);
  unsigned short* WvT = (unsigned short*)(Mb + 1048576);
  unsigned short* WgT = (unsigned short*)(Mb + 1310720);
  // Phase-B overlays inside Mb (M dead after attn_out):
  float* P1 = Mb;                                         // 1024x2048 f32
  float* P3 = Mb + 2097152;                               // 1024x2048 f32
  float* ABb = Mb + 4194304;                              // 1024x2048 f32
  unsigned short* W1T = (unsigned short*)(Mb + 6291456);  // 2048x512 hi+lo = 1048576 f32
  unsigned short* W3T = (unsigned short*)(Mb + 7340032);
  unsigned short* W2T = (unsigned short*)(Mb + 8388608);  // 512x2048 hi+lo = 1048576 f32
  unsigned short* WoT = (unsigned short*)(Mb + 9437184);  // 512x512 hi+lo = 262144 f32
  float* Pa = Mb + 9699328;                               // 524288 f32 (split-K partials)
  float* Pb = Mb + 10223616;                              // 524288 f32
  // Other reuse:
  float* o_buf = part;                                    // 1024x512 f32 (part dead)
  float* h2  = Qb;                                        // (Q dead after build_M)
  float* ffb = Kb;                                        // (K dead after build_M)

  // --- attention input projections (split-precision bf16 MFMA) ---
  ln_rows<<<NTOK, 256, 0, stream>>>(h_in, lnaw, lnab, h_n);
  convT<<<dim3(8, 8), 256, 0, stream>>>(Wq, WqT, 512, 512);
  convT<<<dim3(8, 8), 256, 0, stream>>>(Wk, WkT, 512, 512);
  convT<<<dim3(8, 8), 256, 0, stream>>>(Wv, WvT, 512, 512);
  convT<<<dim3(8, 8), 256, 0, stream>>>(Wg, WgT, 512, 512);
  {
    P4 p = { WqT, WkT, WvT, WgT, Qb, Kb, Vb, Gb };
    gemm_mfma<0><<<dim3(8, 16, 4), 256, 0, stream>>>(h_n, p, 512, 512, 0);
  }
  qk_ln<<<dim3(2048, 2), 256, 0, stream>>>(Qb, Kb);
  build_M<<<dim3(16, 16, 16), 256, 0, stream>>>(Qb, Kb, wrel, x_res, wdist, ggate, Mb);
  hipMemcpyAsync(lvb, lv_prev, 16384 * sizeof(float), hipMemcpyDeviceToDevice, stream);
  for (int it = 0; it < 20; ++it) {
    sink_iter<<<dim3(32, 16), 256, 0, stream>>>(Mb, lvb, mu, OUT_LU, part);
    sink_fin<<<16, 256, 0, stream>>>(part, nu, lvb, (it == 19) ? OUT_LV : nullptr);
  }
  attn_out<<<dim3(16, 16), 256, 0, stream>>>(Mb, OUT_LU, lvb, Vb, Gb, x_res, o_buf, xcb);
  x_update<<<12, 256, 0, stream>>>(x_res, xcb, gamma, OUT_X);

  // --- output projection + FFN (convTs into Mb must run after attn_out) ---
  convT<<<dim3(8, 8), 256, 0, stream>>>(Wo, WoT, 512, 512);
  convT<<<dim3(32, 8), 256, 0, stream>>>(W1, W1T, 512, 2048);
  convT<<<dim3(32, 8), 256, 0, stream>>>(W3, W3T, 512, 2048);
  convT<<<dim3(8, 32), 256, 0, stream>>>(W2, W2T, 2048, 512);
  {
    P4 p = { WoT, WoT, nullptr, nullptr, Pa, Pb, nullptr, nullptr };
    gemm_mfma<1><<<dim3(8, 16, 2), 256, 0, stream>>>(o_buf, p, 512, 512, 256);
  }
  add3<<<512, 256, 0, stream>>>(Pa, Pb, h_in, h2);
  ln_rows<<<NTOK, 256, 0, stream>>>(h2, lnfw, lnfb, ffb);
  {
    P4 p = { W1T, W3T, nullptr, nullptr, P1, P3, nullptr, nullptr };
    gemm_mfma<1><<<dim3(32, 16, 2), 256, 0, stream>>>(ffb, p, 512, 2048, 0);
  }
  silu_mul<<<2048, 256, 0, stream>>>(P1, P3, ABb);
  {
    P4 p = { W2T, W2T, nullptr, nullptr, Pa, Pb, nullptr, nullptr };
    gemm_mfma<1><<<dim3(8, 16, 2), 256, 0, stream>>>(ABb, p, 2048, 512, 1024);
  }
  add3<<<512, 256, 0, stream>>>(Pa, Pb, h2, OUT_H);
}